// Round 2
// baseline (80.300 us; speedup 1.0000x reference)
//
#include <hip/hip_runtime.h>

// DBSCAN neighbor-count + classify via augmented-K bf16 MFMA, MI355X (gfx950)
// B=4, N=8192, D=16 fp32 in, int32 out.
// dist(i,j) < EPS=0.5  <=>  x_i.x_j - g_i - g_j > 0,  g_p = 0.5*||x_p||^2 - EPS^2/4
// Augmented point (24 bf16 = 48 B): [x0..x15, 1.0, -g, 0...]
//   A row i swaps k16..17 to [-g_i, 1]; B col j supplies [1, -g_j]
//   => mfma_f32_16x16x32_bf16 with zero C emits x_i.x_j - g_i - g_j directly.
// out[p] = (count_p < 10) ? -1 : 0
//
// R15: eliminate the atomic output path (untouched R1-R14). Each block now
// owns 64 i-rows and sweeps ALL 8192 j; the 4 waves split j (2048 each),
// each staging 128-j sub-windows into WAVE-PRIVATE double-buffered LDS via
// global_load_lds + counted s_waitcnt vmcnt(6) (no __syncthreads in the
// main loop). Removes: 524K cross-XCD same-address atomicAdds, out
// zero-init, the classify kernel (fused), and all main-loop barriers.
// Cost: B re-read per block = 200 MB L2-resident traffic (~5.8 us agg,
// overlapped). Grid 512 = exactly 2 blocks/CU (LDS 49.2 KB allows 3).

constexpr int Np = 8192;
constexpr int Bb = 4;
constexpr int MIN_PTS = 10;
constexpr float EPS2_4 = 0.0625f;  // EPS^2 / 4
constexpr int ICH = 64;        // i rows per block (shared by all 4 waves)
constexpr int RF = 4;          // A fragments per wave (16 rows each)
constexpr int NWAVE = 4;
constexpr int JPW = Np / NWAVE;   // 2048 j per wave
constexpr int SW = 128;           // j per staged sub-window
constexpr int NSW = JPW / SW;     // 16 sub-windows per wave
constexpr int NT = SW / 16;       // 8 j-tiles per sub-window
constexpr int SWB = SW * 24;      // bf16 elems per sub-window buffer

typedef __bf16 bf16x8 __attribute__((ext_vector_type(8)));
typedef float  f32x4  __attribute__((ext_vector_type(4)));

#define GLOBAL_LOAD_LDS16(gptr, lptr)                                          \
    __builtin_amdgcn_global_load_lds(                                          \
        (const __attribute__((address_space(1))) void*)(gptr),                 \
        (__attribute__((address_space(3))) void*)(lptr), 16, 0, 0)

// ---------------- prep: fp32 -> augmented bf16 in window-tiled layout -------
// slot(p, r) = ((b*16 + js)*32 + tl)*48 + r*16 + m, 16 B per slot, where
// js = (p%8192)/512, tl = (p%512)/16, m = p%16.
__global__ __launch_bounds__(256)
void dbscan_prep(const float* __restrict__ x, __bf16* __restrict__ aug) {
    const int p = blockIdx.x * 256 + threadIdx.x;    // 32768 points
    const float4* src = (const float4*)(x + (size_t)p * 16);
    float4 v0 = src[0], v1 = src[1], v2 = src[2], v3 = src[3];
    float vv[16];
    vv[0]=v0.x; vv[1]=v0.y; vv[2]=v0.z; vv[3]=v0.w;
    vv[4]=v1.x; vv[5]=v1.y; vv[6]=v1.z; vv[7]=v1.w;
    vv[8]=v2.x; vv[9]=v2.y; vv[10]=v2.z; vv[11]=v2.w;
    vv[12]=v3.x; vv[13]=v3.y; vv[14]=v3.z; vv[15]=v3.w;
    float s = 0.f;
#pragma unroll
    for (int k = 0; k < 16; k++) s = fmaf(vv[k], vv[k], s);
    const float g = 0.5f * s - EPS2_4;
    bf16x8 h0, h1, h2;
#pragma unroll
    for (int k = 0; k < 8; k++) { h0[k] = (__bf16)vv[k]; h1[k] = (__bf16)vv[k+8]; }
    h2[0] = (__bf16)1.0f; h2[1] = (__bf16)(-g);
#pragma unroll
    for (int k = 2; k < 8; k++) h2[k] = (__bf16)0.0f;

    const int b   = p >> 13;
    const int pin = p & 8191;
    const int js  = pin >> 9;
    const int tl  = (pin >> 4) & 31;
    const int m   = pin & 15;
    bf16x8* dst = (bf16x8*)aug + (((size_t)(b * 16 + js) * 32 + tl) * 48 + m);
    dst[0]  = h0;   // r = 0
    dst[16] = h1;   // r = 1
    dst[32] = h2;   // r = 2
}

// ---------------- count: atomic-free full-j sweep, classify fused ----------
// grid: 4 b x 128 i-chunks = 512 blocks, 256 threads (4 waves).
__global__ __launch_bounds__(256, 2)
void dbscan_count(const __bf16* __restrict__ aug, int* __restrict__ out) {
    const int lane = threadIdx.x & 63;
    const int w    = threadIdx.x >> 6;
    const int m    = lane & 15;          // A/B row-col within tile
    const int q    = lane >> 4;          // k-chunk; C row group
    const int blk  = blockIdx.x;
    const int b    = blk >> 7;
    const int ic   = blk & 127;
    const int ibase = ic * ICH;

    // Wave-private double-buffered LDS: 4 waves x 2 bufs x 6144 B = 48 KB.
    __shared__ __align__(16) __bf16 ldsB[NWAVE * 2 * SWB];
    __shared__ int partial[NWAVE][ICH];

    // Stage one 128-j sub-window for wave w: pure linear DMA, 6 chunks/lane.
    auto stage = [&](int buf, int sw) {
        const int jj0 = w * JPW + sw * SW;          // 128-aligned within batch
        const int js  = jj0 >> 9;
        const int tl0 = (jj0 >> 4) & 31;            // 8 tiles, never straddles
        const __bf16* src = aug + (((size_t)(b * 16 + js) * 32 + tl0) * 48) * 8;
        __bf16* dst = ldsB + (size_t)(w * 2 + buf) * SWB;
#pragma unroll
        for (int it = 0; it < 6; ++it) {
            const int c = it * 64 + lane;
            GLOBAL_LOAD_LDS16(src + (size_t)c * 8, dst + (size_t)c * 8);
        }
    };

    stage(0, 0);

    // A fragments (global, loop-invariant, coalesced). Rows: ibase + f*16 + m.
    bf16x8 af[RF];
    const int qa = (q < 3) ? q : 2;      // q==3 clamps to a valid addr, zeroed
#pragma unroll
    for (int f = 0; f < RF; f++) {
        const int rowbase = ibase + f * 16;          // uniform, mult of 16
        const int jsA = rowbase >> 9;
        const int tlA = (rowbase >> 4) & 31;
        const __bf16* ap = aug +
            (((size_t)(b * 16 + jsA) * 32 + tlA) * 48 + qa * 16 + m) * 8;
        bf16x8 a = *(const bf16x8*)ap;
        if (q == 2) { __bf16 t = a[0]; a[0] = a[1]; a[1] = t; }  // [1,-g]->[-g,1]
        if (q == 3) {
#pragma unroll
            for (int k = 0; k < 8; k++) a[k] = (__bf16)0.0f;
        }
        af[f] = a;
    }

    const f32x4 zacc = {0.f, 0.f, 0.f, 0.f};
    int cnt[16];
#pragma unroll
    for (int i = 0; i < 16; i++) cnt[i] = 0;

    // B fragment LDS offset: q<3 -> slot q*16+m; q==3 -> slot 0 (dead input)
    const int boff = (q < 3 ? (q * 16 + m) * 8 : 0);

    int buf = 0;
    for (int sw = 0; sw < NSW; ++sw) {
        if (sw + 1 < NSW) {
            stage(buf ^ 1, sw + 1);                       // prefetch next
            asm volatile("s_waitcnt vmcnt(6)" ::: "memory");  // cur complete
        } else {
            asm volatile("s_waitcnt vmcnt(0)" ::: "memory");
        }
        __builtin_amdgcn_sched_barrier(0);
        const __bf16* base = ldsB + (size_t)(w * 2 + buf) * SWB + boff;
#pragma unroll
        for (int t = 0; t < NT; ++t) {
            bf16x8 bc = *(const bf16x8*)(base + t * 48 * 8);
#pragma unroll
            for (int f = 0; f < RF; f++) {
                f32x4 acc = __builtin_amdgcn_mfma_f32_16x16x32_bf16(af[f], bc, zacc, 0, 0, 0);
                // sign-bit accumulate: adds -1 per NEGATIVE result.
                cnt[f*4+0] += __float_as_int(acc[0]) >> 31;
                cnt[f*4+1] += __float_as_int(acc[1]) >> 31;
                cnt[f*4+2] += __float_as_int(acc[2]) >> 31;
                cnt[f*4+3] += __float_as_int(acc[3]) >> 31;
            }
        }
        buf ^= 1;
    }

    // Sum across the 16 cols (lane bits 0..3).
#pragma unroll
    for (int i = 0; i < 16; i++) {
        int v = cnt[i];
        v += __shfl_xor(v, 1);
        v += __shfl_xor(v, 2);
        v += __shfl_xor(v, 4);
        v += __shfl_xor(v, 8);
        cnt[i] = v;
    }
    if (m == 0) {
#pragma unroll
        for (int f = 0; f < RF; f++)
#pragma unroll
            for (int r = 0; r < 4; r++)
                partial[w][f * 16 + q * 4 + r] = cnt[f*4 + r];
    }
    __syncthreads();   // the only block-wide barrier in the kernel

    if (threadIdx.x < ICH) {
        const int row = threadIdx.x;
        const int s = partial[0][row] + partial[1][row] +
                      partial[2][row] + partial[3][row];
        const int count = Np + s;   // positives = Np + sum(-1 per negative)
        out[(size_t)b * Np + ibase + row] = (count < MIN_PTS) ? -1 : 0;
    }
}

extern "C" void kernel_launch(void* const* d_in, const int* in_sizes, int n_in,
                              void* d_out, int out_size, void* d_ws, size_t ws_size,
                              hipStream_t stream) {
    const float* x = (const float*)d_in[0];
    int* out = (int*)d_out;
    __bf16* aug = (__bf16*)d_ws;   // 4*16*32*48*16 B = 1.5 MB, window-tiled

    dbscan_prep<<<dim3(Bb * Np / 256), dim3(256), 0, stream>>>(x, aug);
    dbscan_count<<<dim3(Bb * (Np / ICH)), dim3(256), 0, stream>>>(aug, out);
}

// Round 3
// 75.897 us; speedup vs baseline: 1.0580x; 1.0580x over previous
//
#include <hip/hip_runtime.h>

// DBSCAN neighbor-count + classify via augmented-K bf16 MFMA, MI355X (gfx950)
// B=4, N=8192, D=16 fp32 in, int32 out.
// dist(i,j) < EPS=0.5  <=>  x_i.x_j - g_i - g_j > 0,  g_p = 0.5*||x_p||^2 - EPS^2/4
// Augmented point (24 bf16 = 48 B): [x0..x15, 1.0, -g, 0...]
//   A row i swaps k16..17 to [-g_i, 1]; B col j supplies [1, -g_j]
//   => mfma_f32_16x16x32_bf16 with zero C emits x_i.x_j - g_i - g_j directly.
// out[p] = (count_p < 10) ? -1 : 0
//
// R16 = R14 structure (76.0us: window-tiled aug layout, global_load_lds
// staging, atomic partials — R15 proved the atomic-free restructure LOSES
// via occupancy) + rare-positive epilogue. Pipe model: MFMA ~8.3us, old
// sign-accumulate epilogue ~9.4us VALU -> VALU-co-bound. Domain fact: with
// 16-dim normal data, dist<EPS fires ~only on the diagonal, so positives
// are rare. New epilogue: count POSITIVES, gated by a wave-uniform
// any-positive test (v_max3 tree + __ballot + scalar branch). Fast path
// ~9 VALU per 16 results vs 32; slow path only on diagonal groups
// (~4/128 groups in 1/16 blocks). MFMA numerics unchanged.

constexpr int Np = 8192;
constexpr int Bb = 4;
constexpr int MIN_PTS = 10;
constexpr float EPS2_4 = 0.0625f;  // EPS^2 / 4
constexpr int JS = 16;         // j-windows per batch
constexpr int JW = Np / JS;    // 512 j per window/block
constexpr int ICH = 256;       // i rows per block (4 waves x 64)
constexpr int RF = 4;          // A fragments per wave (16 rows each)
constexpr int NT = JW / 16;    // 32 j-tiles per window

typedef __bf16 bf16x8 __attribute__((ext_vector_type(8)));
typedef float  f32x4  __attribute__((ext_vector_type(4)));

#define GLOBAL_LOAD_LDS16(gptr, lptr)                                          \
    __builtin_amdgcn_global_load_lds(                                          \
        (const __attribute__((address_space(1))) void*)(gptr),                 \
        (__attribute__((address_space(3))) void*)(lptr), 16, 0, 0)

// ---------------- prep: fp32 -> augmented bf16 in window-tiled layout -------
// slot(p, r) = ((b*16 + js)*32 + tl)*48 + r*16 + m, 16 B per slot, where
// js = (p%8192)/512, tl = (p%512)/16, m = p%16.
__global__ __launch_bounds__(256)
void dbscan_prep(const float* __restrict__ x, __bf16* __restrict__ aug,
                 int* __restrict__ out) {
    const int p = blockIdx.x * 256 + threadIdx.x;    // 32768 points
    const float4* src = (const float4*)(x + (size_t)p * 16);
    float4 v0 = src[0], v1 = src[1], v2 = src[2], v3 = src[3];
    float vv[16];
    vv[0]=v0.x; vv[1]=v0.y; vv[2]=v0.z; vv[3]=v0.w;
    vv[4]=v1.x; vv[5]=v1.y; vv[6]=v1.z; vv[7]=v1.w;
    vv[8]=v2.x; vv[9]=v2.y; vv[10]=v2.z; vv[11]=v2.w;
    vv[12]=v3.x; vv[13]=v3.y; vv[14]=v3.z; vv[15]=v3.w;
    float s = 0.f;
#pragma unroll
    for (int k = 0; k < 16; k++) s = fmaf(vv[k], vv[k], s);
    const float g = 0.5f * s - EPS2_4;
    bf16x8 h0, h1, h2;
#pragma unroll
    for (int k = 0; k < 8; k++) { h0[k] = (__bf16)vv[k]; h1[k] = (__bf16)vv[k+8]; }
    h2[0] = (__bf16)1.0f; h2[1] = (__bf16)(-g);
#pragma unroll
    for (int k = 2; k < 8; k++) h2[k] = (__bf16)0.0f;

    const int b   = p >> 13;
    const int pin = p & 8191;
    const int js  = pin >> 9;
    const int tl  = (pin >> 4) & 31;
    const int m   = pin & 15;
    bf16x8* dst = (bf16x8*)aug + (((size_t)(b * 16 + js) * 32 + tl) * 48 + m);
    dst[0]  = h0;   // r = 0
    dst[16] = h1;   // r = 1
    dst[32] = h2;   // r = 2
    out[p] = 0;
}

// ---------------- count: DMA-staged Gram sweep, atomicAdd partials ----------
// grid: 4 b x 32 i-chunks x 16 j-windows = 2048 blocks, 256 threads.
__global__ __launch_bounds__(256, 6)
void dbscan_count(const __bf16* __restrict__ aug, int* __restrict__ out) {
    const int lane = threadIdx.x & 63;
    const int w    = threadIdx.x >> 6;
    const int m    = lane & 15;          // A/B row-col within tile
    const int q    = lane >> 4;          // k-chunk; C row group
    const int blk  = blockIdx.x;
    const int b    = blk >> 9;
    const int ic   = (blk >> 4) & 31;
    const int js   = blk & 15;
    const int ibase = ic * ICH;

    // LDS image == global window image: [tile][r][m] x 16 B. 24.6 KB.
    __shared__ __bf16 ldsB[NT * 48 * 8];

    // Stage window: pure linear async DMA, 1536 16B-chunks, 6 per thread.
    {
        const __bf16* src = aug + ((size_t)(b * 16 + js) * 32) * 48 * 8;
#pragma unroll
        for (int it = 0; it < 6; it++) {
            const int c = threadIdx.x + it * 256;
            GLOBAL_LOAD_LDS16(src + (size_t)c * 8, ldsB + (size_t)c * 8);
        }
    }

    // A fragments (global, loop-invariant, coalesced: wave reads 1024
    // contiguous B per fragment). Rows: ibase + w*64 + f*16 + m.
    bf16x8 af[RF];
    const int qa = (q < 3) ? q : 2;      // q==3 clamps to a valid addr, zeroed
#pragma unroll
    for (int f = 0; f < RF; f++) {
        const int rowbase = ibase + w * 64 + f * 16;     // uniform, mult of 16
        const int jsA = rowbase >> 9;
        const int tlA = (rowbase >> 4) & 31;
        const __bf16* ap = aug +
            (((size_t)(b * 16 + jsA) * 32 + tlA) * 48 + qa * 16 + m) * 8;
        bf16x8 a = *(const bf16x8*)ap;
        if (q == 2) { __bf16 t = a[0]; a[0] = a[1]; a[1] = t; }  // [1,-g]->[-g,1]
        if (q == 3) {
#pragma unroll
            for (int k = 0; k < 8; k++) a[k] = (__bf16)0.0f;
        }
        af[f] = a;
    }

    __syncthreads();   // drains vmcnt(0): DMA staging complete

    // B fragment address: q<3 -> slot q*16+m; q==3 -> broadcast slot 0 (dead)
    const __bf16* bptr = ldsB + (q < 3 ? (q * 16 + m) * 8 : 0);

    const f32x4 zacc = {0.f, 0.f, 0.f, 0.f};
    int cnt[16];
#pragma unroll
    for (int i = 0; i < 16; i++) cnt[i] = 0;

    bf16x8 bc = *(const bf16x8*)bptr;
#pragma unroll 2
    for (int t = 0; t < NT; t++) {
        const int tn = (t + 1) & (NT - 1);
        bf16x8 bn = *(const bf16x8*)(bptr + tn * 48 * 8);   // depth-1 prefetch
        f32x4 acc[RF];
#pragma unroll
        for (int f = 0; f < RF; f++)
            acc[f] = __builtin_amdgcn_mfma_f32_16x16x32_bf16(af[f], bc, zacc, 0, 0, 0);
        // Rare-positive gate: neighbors (acc>0) are ~diagonal-only for this
        // data. Wave-uniform skip of the accumulate when no lane has one.
        float gm = acc[0][0];
#pragma unroll
        for (int f = 0; f < RF; f++) {
            gm = fmaxf(gm, fmaxf(fmaxf(acc[f][0], acc[f][1]),
                                 fmaxf(acc[f][2], acc[f][3])));
        }
        if (__ballot(gm > 0.0f) != 0ull) {   // scalar branch, rare
#pragma unroll
            for (int f = 0; f < RF; f++) {
                cnt[f*4+0] += (acc[f][0] > 0.0f) ? 1 : 0;
                cnt[f*4+1] += (acc[f][1] > 0.0f) ? 1 : 0;
                cnt[f*4+2] += (acc[f][2] > 0.0f) ? 1 : 0;
                cnt[f*4+3] += (acc[f][3] > 0.0f) ? 1 : 0;
            }
        }
        bc = bn;
    }

    // Sum across the 16 cols (lane bits 0..3); lane m==0 of each q adds rows.
#pragma unroll
    for (int i = 0; i < 16; i++) {
        int v = cnt[i];
        v += __shfl_xor(v, 1);
        v += __shfl_xor(v, 2);
        v += __shfl_xor(v, 4);
        v += __shfl_xor(v, 8);
        cnt[i] = v;
    }
    if (m == 0) {
        int* ob = out + (size_t)b * Np + ibase + w * 64;
#pragma unroll
        for (int f = 0; f < RF; f++)
#pragma unroll
            for (int r = 0; r < 4; r++)
                atomicAdd(&ob[f*16 + q*4 + r], cnt[f*4+r]);
    }
}

// ---------------- classify ----------------
__global__ __launch_bounds__(256)
void dbscan_classify(int* __restrict__ out) {
    const int p = blockIdx.x * 256 + threadIdx.x;
    out[p] = (out[p] < MIN_PTS) ? -1 : 0;
}

extern "C" void kernel_launch(void* const* d_in, const int* in_sizes, int n_in,
                              void* d_out, int out_size, void* d_ws, size_t ws_size,
                              hipStream_t stream) {
    const float* x = (const float*)d_in[0];
    int* out = (int*)d_out;
    __bf16* aug = (__bf16*)d_ws;   // 4*16*32*48*16 B = 1.5 MB, window-tiled

    dbscan_prep<<<dim3(Bb * Np / 256), dim3(256), 0, stream>>>(x, aug, out);
    dbscan_count<<<dim3(Bb * 32 * JS), dim3(256), 0, stream>>>(aug, out);
    dbscan_classify<<<dim3(Bb * Np / 256), dim3(256), 0, stream>>>(out);
}